// Round 2
// baseline (2042.900 us; speedup 1.0000x reference)
//
#include <hip/hip_runtime.h>
#include <hip/hip_bf16.h>
#include <cstdint>

// InterModalityUpdate — f32 in/out, bf16 MFMA internally (fp32 accum).
// R4: LDS-staged coalesced GEMM epilogue (fixes partial-dirty-line eviction:
//     WRITE_SIZE was 2x ideal, FETCH +100MB RFO); attn Qs/Ps LDS union (3->4 blocks/CU).
// R5/R6: infra failed twice on identical resubmits. This round: baseline +
//     T5 s_setprio around attn MFMA clusters only (m191 regime: independent
//     blocks, multi-block/CU — measured +4-7% on attn; NOT applied to the
//     lockstep 4-wave GEMM, m190's null regime). Zero sync-structure change.
// Dims fixed: B=16 N=M=512 VS=2048 QS=1024 OS=2048 H=16 DH=128.

typedef __hip_bfloat16 bf16;
typedef __attribute__((ext_vector_type(8))) __bf16 bf16x8;
typedef __attribute__((ext_vector_type(4))) float f32x4;
typedef __attribute__((ext_vector_type(4))) unsigned short us4;
typedef __attribute__((ext_vector_type(8))) unsigned short us8;

#define AS1 __attribute__((address_space(1)))
#define AS3 __attribute__((address_space(3)))

__device__ __forceinline__ void gl_lds16(const bf16* g, bf16* l) {
    __builtin_amdgcn_global_load_lds((AS1 void*)(uintptr_t)(g), (AS3 void*)(l), 16, 0, 0);
}

__device__ __forceinline__ bf16x8 ld8(const bf16* p) { return *(const bf16x8*)p; }

__device__ __forceinline__ f32x4 mfma16(bf16x8 a, bf16x8 b, f32x4 c) {
    return __builtin_amdgcn_mfma_f32_16x16x32_bf16(a, b, c, 0, 0, 0);
}

// f32 -> bf16 bits, round-to-nearest-even (finite inputs)
__device__ __forceinline__ unsigned short f2bs(float f) {
    unsigned u = __builtin_bit_cast(unsigned, f);
    unsigned r = u + 0x7FFFu + ((u >> 16) & 1u);
    return (unsigned short)(r >> 16);
}

// ---------------------------------------------------------------------------
// f32 -> bf16 convert into left columns of a wider bf16 matrix. 8 elems/thread.
__global__ __launch_bounds__(256) void cvt_cols_k(
    const float* __restrict__ src, bf16* __restrict__ dst,
    int cprShift, int dstStride, int totalChunks)
{
    const int id = blockIdx.x * 256 + threadIdx.x;
    if (id >= totalChunks) return;
    const int row = id >> cprShift;
    const int cc = (id - (row << cprShift)) << 3;
    const float* s = src + ((size_t)row << (cprShift + 3)) + cc;
    const float4 a = *(const float4*)s;
    const float4 b = *(const float4*)(s + 4);
    us8 o;
    o[0] = f2bs(a.x); o[1] = f2bs(a.y); o[2] = f2bs(a.z); o[3] = f2bs(a.w);
    o[4] = f2bs(b.x); o[5] = f2bs(b.y); o[6] = f2bs(b.z); o[7] = f2bs(b.w);
    *(us8*)(dst + (size_t)row * dstStride + cc) = o;
}

// ---------------------------------------------------------------------------
// Fused convert+transpose for weights. f32 R x C -> bf16 C x R.
__global__ __launch_bounds__(256) void cvt_transpose_k(
    const float* __restrict__ in, unsigned short* __restrict__ out,
    int inStride, int outStride)
{
    __shared__ unsigned short tile[64][65];
    const int ti = blockIdx.x * 64;
    const int tj = blockIdx.y * 64;
    const int t = threadIdx.x;
    const int r = t >> 4;
    const int c4 = (t & 15) << 2;
#pragma unroll
    for (int i = 0; i < 4; ++i) {
        const float4 v = *(const float4*)(in + (size_t)(tj + r + i * 16) * inStride + ti + c4);
        tile[r + i * 16][c4 + 0] = f2bs(v.x);
        tile[r + i * 16][c4 + 1] = f2bs(v.y);
        tile[r + i * 16][c4 + 2] = f2bs(v.z);
        tile[r + i * 16][c4 + 3] = f2bs(v.w);
    }
    __syncthreads();
#pragma unroll
    for (int i = 0; i < 4; ++i) {
        const int orow = ti + r + i * 16;
        us4 v;
        v[0] = tile[c4 + 0][r + i * 16];
        v[1] = tile[c4 + 1][r + i * 16];
        v[2] = tile[c4 + 2][r + i * 16];
        v[3] = tile[c4 + 3][r + i * 16];
        *(us4*)(out + (size_t)orow * outStride + tj + c4) = v;
    }
}

// ---------------------------------------------------------------------------
// bf16 tiled transpose (per-head value slices). grid.z slice offset:
// (z>>4)*inOffB + (z&15)*inOffH.
__global__ __launch_bounds__(256) void transpose_k(
    const unsigned short* __restrict__ in, unsigned short* __restrict__ out,
    int inStride, int outStride, size_t inOffB, int inOffH, size_t outSliceStride)
{
    __shared__ unsigned short tile[64][65];
    const int z = blockIdx.z;
    const unsigned short* inp = in + (size_t)(z >> 4) * inOffB + (size_t)(z & 15) * inOffH;
    unsigned short* outp = out + (size_t)z * outSliceStride;
    const int ti = blockIdx.x * 64;
    const int tj = blockIdx.y * 64;
    const int t = threadIdx.x;
    const int r = t >> 4;
    const int c4 = (t & 15) << 2;
#pragma unroll
    for (int i = 0; i < 4; ++i) {
        us4 v = *(const us4*)(inp + (size_t)(tj + r + i * 16) * inStride + ti + c4);
        tile[r + i * 16][c4 + 0] = v[0];
        tile[r + i * 16][c4 + 1] = v[1];
        tile[r + i * 16][c4 + 2] = v[2];
        tile[r + i * 16][c4 + 3] = v[3];
    }
    __syncthreads();
#pragma unroll
    for (int i = 0; i < 4; ++i) {
        const int orow = ti + r + i * 16;
        us4 v;
        v[0] = tile[c4 + 0][r + i * 16];
        v[1] = tile[c4 + 1][r + i * 16];
        v[2] = tile[c4 + 2][r + i * 16];
        v[3] = tile[c4 + 3][r + i * 16];
        *(us4*)(outp + (size_t)orow * outStride + tj + c4) = v;
    }
}

// ---------------------------------------------------------------------------
// C = relu(A @ B + bias) [* mask[row]]; BT[n][k]. 128x128 tile, BK=32, 4 waves.
// Epilogue staged through LDS for linear, line-complete global stores.
template <typename OutT>
__global__ __launch_bounds__(256) void gemm_bt(
    const bf16* __restrict__ A, const bf16* __restrict__ BT,
    const float* __restrict__ bias, const float* __restrict__ mask,
    OutT* __restrict__ C, int K, int lda, int ldb, int ldc)
{
    __shared__ __align__(16) bf16 smem[8192];   // As | Bs; reused as epilogue staging
    bf16* As = smem;
    bf16* Bs = smem + 4096;
    const int tid = threadIdx.x;
    const int lane = tid & 63;
    const int l16 = lane & 15;
    const int quad = lane >> 4;
    const int wave = tid >> 6;
    const int wr = (wave >> 1) * 64;
    const int wc = (wave & 1) * 64;
    const size_t row0 = (size_t)blockIdx.y * 128;
    const size_t col0 = (size_t)blockIdx.x * 128;

    const f32x4 z4 = {0.f, 0.f, 0.f, 0.f};
    f32x4 acc[4][4];
#pragma unroll
    for (int r = 0; r < 4; ++r)
#pragma unroll
        for (int c = 0; c < 4; ++c) acc[r][c] = z4;

    const int e1 = tid * 8;
    const int m1 = e1 >> 5, k1 = e1 & 31;
    const int e2 = e1 + 2048;
    const int m2 = e2 >> 5, k2 = e2 & 31;

    for (int k0 = 0; k0 < K; k0 += 32) {
        gl_lds16(A  + (row0 + m1) * lda + k0 + k1, As + e1);
        gl_lds16(A  + (row0 + m2) * lda + k0 + k2, As + e2);
        gl_lds16(BT + (col0 + m1) * ldb + k0 + k1, Bs + e1);
        gl_lds16(BT + (col0 + m2) * ldb + k0 + k2, Bs + e2);
        __syncthreads();
        bf16x8 af[4], bfv[4];
#pragma unroll
        for (int r = 0; r < 4; ++r)
            af[r] = ld8(As + (wr + r * 16 + l16) * 32 + quad * 8);
#pragma unroll
        for (int c = 0; c < 4; ++c)
            bfv[c] = ld8(Bs + (wc + c * 16 + l16) * 32 + quad * 8);
#pragma unroll
        for (int r = 0; r < 4; ++r)
#pragma unroll
            for (int c = 0; c < 4; ++c)
                acc[r][c] = mfma16(af[r], bfv[c], acc[r][c]);
        __syncthreads();
    }

    // fragment value (bias+relu+mask), D row = quad*4+reg, col = l16
    float bcol[4];
#pragma unroll
    for (int c = 0; c < 4; ++c) bcol[c] = bias[col0 + wc + c * 16 + l16];

    if constexpr (sizeof(OutT) == 2) {
        // bf16 out: 4 passes x 32 rows; staging stride 136 (bank-friendly)
        bf16* stg = smem;
#pragma unroll
        for (int p = 0; p < 4; ++p) {
            if (wr == (p >> 1) * 64) {
#pragma unroll
                for (int rr = 0; rr < 2; ++rr) {
                    const int r = (p & 1) * 2 + rr;
#pragma unroll
                    for (int c = 0; c < 4; ++c) {
                        const int lcol = wc + c * 16 + l16;
#pragma unroll
                        for (int g = 0; g < 4; ++g) {
                            const int lrow = rr * 16 + quad * 4 + g;
                            const size_t grow = row0 + wr + r * 16 + quad * 4 + g;
                            float v = acc[r][c][g] + bcol[c];
                            v = v > 0.f ? v : 0.f;
                            if (mask) v *= mask[grow];
                            ((unsigned short*)stg)[lrow * 136 + lcol] = f2bs(v);
                        }
                    }
                }
            }
            asm volatile("" ::: "memory");
            __syncthreads();
            const int srow = tid >> 3;            // 0..31
            const int scol = (tid & 7) * 16;      // 0..112
            const us8 o0 = *(const us8*)((unsigned short*)stg + srow * 136 + scol);
            const us8 o1 = *(const us8*)((unsigned short*)stg + srow * 136 + scol + 8);
            OutT* dst = C + (row0 + p * 32 + srow) * ldc + col0 + scol;
            *(us8*)dst = o0;
            *(us8*)(dst + 8) = o1;
            __syncthreads();
        }
    } else {
        // f32 out: 8 passes x 16 rows; staging stride 132 f32
        float* stg = (float*)smem;
#pragma unroll
        for (int p = 0; p < 8; ++p) {
            if (wr == (p >> 2) * 64) {
                const int r = p & 3;
#pragma unroll
                for (int c = 0; c < 4; ++c) {
                    const int lcol = wc + c * 16 + l16;
#pragma unroll
                    for (int g = 0; g < 4; ++g) {
                        const int lrow = quad * 4 + g;
                        const size_t grow = row0 + wr + r * 16 + quad * 4 + g;
                        float v = acc[r][c][g] + bcol[c];
                        v = v > 0.f ? v : 0.f;
                        if (mask) v *= mask[grow];
                        stg[lrow * 132 + lcol] = v;
                    }
                }
            }
            asm volatile("" ::: "memory");
            __syncthreads();
            const int srow = tid >> 4;            // 0..15
            const int scol = (tid & 15) * 8;      // 0..120
            const f32x4 o0 = *(const f32x4*)(stg + srow * 132 + scol);
            const f32x4 o1 = *(const f32x4*)(stg + srow * 132 + scol + 4);
            OutT* dst = C + (row0 + p * 16 + srow) * ldc + col0 + scol;
            *(f32x4*)dst = o0;
            *(f32x4*)(dst + 4) = o1;
            __syncthreads();
        }
    }
}

// ---------------------------------------------------------------------------
// Cross attention. grid.x = Lq/32, grid.y = B*H. 128 thr = 2 waves x 16 q-rows.
// S in registers (16x512/wave), softmax via 16-lane shuffle reduce,
// P LDS round-trip (C-layout -> A-layout). Qs/Ps share one LDS buffer.
// T5: setprio(1) around MFMA clusters (independent blocks, m191 regime).
__global__ __launch_bounds__(128) void attn_k(
    const bf16* __restrict__ Q, const bf16* __restrict__ Kk,
    const bf16* __restrict__ VT, const float* __restrict__ kmask,
    bf16* __restrict__ Out,
    int Lq, int Lk, int qStride, int kStride, int outStride, int outColOff)
{
    const int bh = blockIdx.y;
    const int b = bh >> 4, h = bh & 15;
    const int n0 = blockIdx.x * 32;
    const int tid = threadIdx.x;
    const int wave = tid >> 6, lane = tid & 63;
    const int l16 = lane & 15, quad = lane >> 4;

    __shared__ __align__(16) bf16 smem[16640];  // Qs(32x128) then Ps[2][16x520]

    // stage Q tile (32 rows x 128 d)
#pragma unroll
    for (int i = 0; i < 4; ++i) {
        const int e = i * 1024 + tid * 8;
        const int r = e >> 7, d = e & 127;
        gl_lds16(Q + (size_t)(b * Lq + n0 + r) * qStride + h * 128 + d, smem + e);
    }
    __syncthreads();

    bf16x8 aq[4];
#pragma unroll
    for (int ks = 0; ks < 4; ++ks)
        aq[ks] = ld8(smem + (wave * 16 + l16) * 128 + ks * 32 + quad * 8);
    __syncthreads();   // union: both waves done reading Qs before Ps overwrites

    // QK^T: B-frag (K rows) straight from global, contiguous-k
    const bf16* Kg = Kk + (size_t)b * Lk * kStride + (size_t)l16 * kStride + h * 128 + quad * 8;
    f32x4 S[32];
    __builtin_amdgcn_s_setprio(1);
#pragma unroll
    for (int t = 0; t < 32; ++t) {
        const bf16* kp = Kg + (size_t)t * 16 * kStride;
        f32x4 c = {0.f, 0.f, 0.f, 0.f};
        c = mfma16(aq[0], ld8(kp), c);
        c = mfma16(aq[1], ld8(kp + 32), c);
        c = mfma16(aq[2], ld8(kp + 64), c);
        c = mfma16(aq[3], ld8(kp + 96), c);
        S[t] = c;
    }
    __builtin_amdgcn_s_setprio(0);

    const float scale = 0.08838834764831845f;  // 1/sqrt(128)
    float mx[4] = {-3.0e38f, -3.0e38f, -3.0e38f, -3.0e38f};
#pragma unroll
    for (int t = 0; t < 32; ++t)
#pragma unroll
        for (int g = 0; g < 4; ++g) mx[g] = fmaxf(mx[g], S[t][g]);
#pragma unroll
    for (int off = 1; off < 16; off <<= 1)
#pragma unroll
        for (int g = 0; g < 4; ++g) mx[g] = fmaxf(mx[g], __shfl_xor(mx[g], off));

    float sm[4] = {0.f, 0.f, 0.f, 0.f};
    const float* mrow = kmask + (size_t)b * Lk;
#pragma unroll
    for (int t = 0; t < 32; ++t) {
        const float mv = mrow[t * 16 + l16];
#pragma unroll
        for (int g = 0; g < 4; ++g) {
            float p = (mv != 0.f) ? __expf((S[t][g] - mx[g]) * scale) : 0.f;
            S[t][g] = p;
            sm[g] += p;
        }
    }
#pragma unroll
    for (int off = 1; off < 16; off <<= 1)
#pragma unroll
        for (int g = 0; g < 4; ++g) sm[g] += __shfl_xor(sm[g], off);
    float rs[4];
#pragma unroll
    for (int g = 0; g < 4; ++g) rs[g] = 1.f / sm[g];

    // P: C-layout regs -> LDS [row16][520]
    bf16* pw = smem + wave * 8320;
#pragma unroll
    for (int t = 0; t < 32; ++t) {
        const int col = t * 16 + l16;
#pragma unroll
        for (int g = 0; g < 4; ++g)
            pw[(quad * 4 + g) * 520 + col] = __float2bfloat16(S[t][g] * rs[g]);
    }
    asm volatile("" ::: "memory");
    __syncthreads();

    bf16x8 pa[16];
#pragma unroll
    for (int ks = 0; ks < 16; ++ks)
        pa[ks] = ld8(pw + l16 * 520 + ks * 32 + quad * 8);

    // PV: B-frag from pre-transposed V^T [bh][d][m], contiguous-m
    const bf16* Vg = VT + (size_t)bh * 128 * Lk + (size_t)l16 * Lk + quad * 8;
    const size_t orow = (size_t)b * Lq + n0 + wave * 16 + quad * 4;
    __builtin_amdgcn_s_setprio(1);
#pragma unroll
    for (int dt = 0; dt < 8; ++dt) {
        const bf16* vp = Vg + (size_t)dt * 16 * Lk;
        f32x4 c = {0.f, 0.f, 0.f, 0.f};
#pragma unroll
        for (int ks = 0; ks < 16; ++ks)
            c = mfma16(pa[ks], ld8(vp + ks * 32), c);
        const int col = outColOff + h * 128 + dt * 16 + l16;
#pragma unroll
        for (int g = 0; g < 4; ++g)
            Out[(orow + g) * outStride + col] = __float2bfloat16(c[g]);
    }
    __builtin_amdgcn_s_setprio(0);
}

// ---------------------------------------------------------------------------
extern "C" void kernel_launch(void* const* d_in, const int* in_sizes, int n_in,
                              void* d_out, int out_size, void* d_ws, size_t ws_size,
                              hipStream_t stream)
{
    (void)in_sizes; (void)n_in; (void)out_size; (void)ws_size;
    const float* v   = (const float*)d_in[0];
    const float* q   = (const float*)d_in[1];
    const float* vm  = (const float*)d_in[2];
    const float* qm  = (const float*)d_in[3];
    const float* Wv  = (const float*)d_in[4];
    const float* bv  = (const float*)d_in[5];
    const float* Wq  = (const float*)d_in[6];
    const float* bq  = (const float*)d_in[7];
    const float* Wvo = (const float*)d_in[8];
    const float* bvo = (const float*)d_in[9];
    const float* Wqo = (const float*)d_in[10];
    const float* bqo = (const float*)d_in[11];

    float* out_v = (float*)d_out;
    float* out_q = out_v + (size_t)8192 * 2048;

    bf16* ws = (bf16*)d_ws;
    bf16* v_trans = ws; ws += (size_t)8192 * 6144;
    bf16* q_trans = ws; ws += (size_t)8192 * 6144;
    bf16* vcat    = ws; ws += (size_t)8192 * 4096;   // [v(bf16) | v_update]
    bf16* qcat    = ws; ws += (size_t)8192 * 3072;   // [q(bf16) | q_update]
    bf16* WvT     = ws; ws += (size_t)6144 * 2048;
    bf16* WqT     = ws; ws += (size_t)6144 * 1024;
    bf16* WvoT    = ws; ws += (size_t)2048 * 4096;
    bf16* WqoT    = ws; ws += (size_t)2048 * 3072;
    bf16* VvalT   = ws; ws += (size_t)256 * 128 * 512;
    bf16* QvalT   = ws; ws += (size_t)256 * 128 * 512;
    // 432 MiB of d_ws

    // 1) convert inputs to bf16 into concat-left (also the GEMM A operands)
    cvt_cols_k<<<8192, 256, 0, stream>>>(v, vcat, 8, 4096, 8192 * 256);
    cvt_cols_k<<<4096, 256, 0, stream>>>(q, qcat, 7, 3072, 8192 * 128);

    // 2) weight convert+transpose (f32 R x C -> bf16 C x R)
    cvt_transpose_k<<<dim3(96, 32), 256, 0, stream>>>(Wv,  (unsigned short*)WvT,  6144, 2048);
    cvt_transpose_k<<<dim3(96, 16), 256, 0, stream>>>(Wq,  (unsigned short*)WqT,  6144, 1024);
    cvt_transpose_k<<<dim3(32, 64), 256, 0, stream>>>(Wvo, (unsigned short*)WvoT, 2048, 4096);
    cvt_transpose_k<<<dim3(32, 48), 256, 0, stream>>>(Wqo, (unsigned short*)WqoT, 2048, 3072);

    // 3) input projections
    gemm_bt<bf16><<<dim3(48, 64), 256, 0, stream>>>(vcat, WvT, bv, vm, v_trans, 2048, 4096, 2048, 6144);
    gemm_bt<bf16><<<dim3(48, 64), 256, 0, stream>>>(qcat, WqT, bq, qm, q_trans, 1024, 3072, 1024, 6144);

    // 4) value-slice transposes: [b,n,h,d] -> [bh][d][n]
    transpose_k<<<dim3(2, 8, 256), 256, 0, stream>>>((const unsigned short*)(v_trans + 4096), (unsigned short*)VvalT,
                                                     6144, 512, (size_t)512 * 6144, 128, 65536);
    transpose_k<<<dim3(2, 8, 256), 256, 0, stream>>>((const unsigned short*)(q_trans + 4096), (unsigned short*)QvalT,
                                                     6144, 512, (size_t)512 * 6144, 128, 65536);

    // 5) cross attention
    attn_k<<<dim3(16, 256), 128, 0, stream>>>(v_trans + 2048, q_trans, QvalT, qm, vcat,
                                              512, 512, 6144, 6144, 4096, 2048);
    attn_k<<<dim3(16, 256), 128, 0, stream>>>(q_trans + 2048, v_trans, VvalT, vm, qcat,
                                              512, 512, 6144, 6144, 3072, 1024);

    // 6) output projections -> d_out (f32, LDS-staged stores)
    gemm_bt<float><<<dim3(16, 64), 256, 0, stream>>>(vcat, WvoT, bvo, nullptr, out_v, 4096, 4096, 4096, 2048);
    gemm_bt<float><<<dim3(16, 64), 256, 0, stream>>>(qcat, WqoT, bqo, nullptr, out_q, 3072, 3072, 3072, 2048);
}

// Round 3
// 1597.688 us; speedup vs baseline: 1.2787x; 1.2787x over previous
//
#include <hip/hip_runtime.h>
#include <hip/hip_bf16.h>
#include <cstdint>

// InterModalityUpdate — f32 in/out, bf16 MFMA internally (fp32 accum).
// R4: LDS-staged coalesced GEMM epilogue; attn Qs/Ps LDS union.
// R7: attn_k was latency-serialized (MfmaUtil 3.3%, 411us/dispatch): VGPR=144
//     (S[32]+aq consume all) => per-MFMA global ld8s could not pipeline, each
//     paid ~900cy. Fix: K/V staged via global_load_lds (zero-VGPR async DMA),
//     m97-style 2-barrier single-buffer tiles, XOR-swizzled source+read
//     (rule #21; linear LDS dest). kt loop fully unrolled (rule #20).
// Dims fixed: B=16 N=M=512 VS=2048 QS=1024 OS=2048 H=16 DH=128.

typedef __hip_bfloat16 bf16;
typedef __attribute__((ext_vector_type(8))) __bf16 bf16x8;
typedef __attribute__((ext_vector_type(4))) float f32x4;
typedef __attribute__((ext_vector_type(4))) unsigned short us4;
typedef __attribute__((ext_vector_type(8))) unsigned short us8;

#define AS1 __attribute__((address_space(1)))
#define AS3 __attribute__((address_space(3)))

__device__ __forceinline__ void gl_lds16(const bf16* g, bf16* l) {
    __builtin_amdgcn_global_load_lds((AS1 void*)(uintptr_t)(g), (AS3 void*)(l), 16, 0, 0);
}

__device__ __forceinline__ bf16x8 ld8(const bf16* p) { return *(const bf16x8*)p; }

__device__ __forceinline__ f32x4 mfma16(bf16x8 a, bf16x8 b, f32x4 c) {
    return __builtin_amdgcn_mfma_f32_16x16x32_bf16(a, b, c, 0, 0, 0);
}

// f32 -> bf16 bits, round-to-nearest-even (finite inputs)
__device__ __forceinline__ unsigned short f2bs(float f) {
    unsigned u = __builtin_bit_cast(unsigned, f);
    unsigned r = u + 0x7FFFu + ((u >> 16) & 1u);
    return (unsigned short)(r >> 16);
}

// ---------------------------------------------------------------------------
// f32 -> bf16 convert into left columns of a wider bf16 matrix. 8 elems/thread.
__global__ __launch_bounds__(256) void cvt_cols_k(
    const float* __restrict__ src, bf16* __restrict__ dst,
    int cprShift, int dstStride, int totalChunks)
{
    const int id = blockIdx.x * 256 + threadIdx.x;
    if (id >= totalChunks) return;
    const int row = id >> cprShift;
    const int cc = (id - (row << cprShift)) << 3;
    const float* s = src + ((size_t)row << (cprShift + 3)) + cc;
    const float4 a = *(const float4*)s;
    const float4 b = *(const float4*)(s + 4);
    us8 o;
    o[0] = f2bs(a.x); o[1] = f2bs(a.y); o[2] = f2bs(a.z); o[3] = f2bs(a.w);
    o[4] = f2bs(b.x); o[5] = f2bs(b.y); o[6] = f2bs(b.z); o[7] = f2bs(b.w);
    *(us8*)(dst + (size_t)row * dstStride + cc) = o;
}

// ---------------------------------------------------------------------------
// Fused convert+transpose for weights. f32 R x C -> bf16 C x R.
__global__ __launch_bounds__(256) void cvt_transpose_k(
    const float* __restrict__ in, unsigned short* __restrict__ out,
    int inStride, int outStride)
{
    __shared__ unsigned short tile[64][65];
    const int ti = blockIdx.x * 64;
    const int tj = blockIdx.y * 64;
    const int t = threadIdx.x;
    const int r = t >> 4;
    const int c4 = (t & 15) << 2;
#pragma unroll
    for (int i = 0; i < 4; ++i) {
        const float4 v = *(const float4*)(in + (size_t)(tj + r + i * 16) * inStride + ti + c4);
        tile[r + i * 16][c4 + 0] = f2bs(v.x);
        tile[r + i * 16][c4 + 1] = f2bs(v.y);
        tile[r + i * 16][c4 + 2] = f2bs(v.z);
        tile[r + i * 16][c4 + 3] = f2bs(v.w);
    }
    __syncthreads();
#pragma unroll
    for (int i = 0; i < 4; ++i) {
        const int orow = ti + r + i * 16;
        us4 v;
        v[0] = tile[c4 + 0][r + i * 16];
        v[1] = tile[c4 + 1][r + i * 16];
        v[2] = tile[c4 + 2][r + i * 16];
        v[3] = tile[c4 + 3][r + i * 16];
        *(us4*)(out + (size_t)orow * outStride + tj + c4) = v;
    }
}

// ---------------------------------------------------------------------------
// bf16 tiled transpose (per-head value slices). grid.z slice offset:
// (z>>4)*inOffB + (z&15)*inOffH.
__global__ __launch_bounds__(256) void transpose_k(
    const unsigned short* __restrict__ in, unsigned short* __restrict__ out,
    int inStride, int outStride, size_t inOffB, int inOffH, size_t outSliceStride)
{
    __shared__ unsigned short tile[64][65];
    const int z = blockIdx.z;
    const unsigned short* inp = in + (size_t)(z >> 4) * inOffB + (size_t)(z & 15) * inOffH;
    unsigned short* outp = out + (size_t)z * outSliceStride;
    const int ti = blockIdx.x * 64;
    const int tj = blockIdx.y * 64;
    const int t = threadIdx.x;
    const int r = t >> 4;
    const int c4 = (t & 15) << 2;
#pragma unroll
    for (int i = 0; i < 4; ++i) {
        us4 v = *(const us4*)(inp + (size_t)(tj + r + i * 16) * inStride + ti + c4);
        tile[r + i * 16][c4 + 0] = v[0];
        tile[r + i * 16][c4 + 1] = v[1];
        tile[r + i * 16][c4 + 2] = v[2];
        tile[r + i * 16][c4 + 3] = v[3];
    }
    __syncthreads();
#pragma unroll
    for (int i = 0; i < 4; ++i) {
        const int orow = ti + r + i * 16;
        us4 v;
        v[0] = tile[c4 + 0][r + i * 16];
        v[1] = tile[c4 + 1][r + i * 16];
        v[2] = tile[c4 + 2][r + i * 16];
        v[3] = tile[c4 + 3][r + i * 16];
        *(us4*)(outp + (size_t)orow * outStride + tj + c4) = v;
    }
}

// ---------------------------------------------------------------------------
// C = relu(A @ B + bias) [* mask[row]]; BT[n][k]. 128x128 tile, BK=32, 4 waves.
// Epilogue staged through LDS for linear, line-complete global stores.
template <typename OutT>
__global__ __launch_bounds__(256) void gemm_bt(
    const bf16* __restrict__ A, const bf16* __restrict__ BT,
    const float* __restrict__ bias, const float* __restrict__ mask,
    OutT* __restrict__ C, int K, int lda, int ldb, int ldc)
{
    __shared__ __align__(16) bf16 smem[8192];   // As | Bs; reused as epilogue staging
    bf16* As = smem;
    bf16* Bs = smem + 4096;
    const int tid = threadIdx.x;
    const int lane = tid & 63;
    const int l16 = lane & 15;
    const int quad = lane >> 4;
    const int wave = tid >> 6;
    const int wr = (wave >> 1) * 64;
    const int wc = (wave & 1) * 64;
    const size_t row0 = (size_t)blockIdx.y * 128;
    const size_t col0 = (size_t)blockIdx.x * 128;

    const f32x4 z4 = {0.f, 0.f, 0.f, 0.f};
    f32x4 acc[4][4];
#pragma unroll
    for (int r = 0; r < 4; ++r)
#pragma unroll
        for (int c = 0; c < 4; ++c) acc[r][c] = z4;

    const int e1 = tid * 8;
    const int m1 = e1 >> 5, k1 = e1 & 31;
    const int e2 = e1 + 2048;
    const int m2 = e2 >> 5, k2 = e2 & 31;

    for (int k0 = 0; k0 < K; k0 += 32) {
        gl_lds16(A  + (row0 + m1) * lda + k0 + k1, As + e1);
        gl_lds16(A  + (row0 + m2) * lda + k0 + k2, As + e2);
        gl_lds16(BT + (col0 + m1) * ldb + k0 + k1, Bs + e1);
        gl_lds16(BT + (col0 + m2) * ldb + k0 + k2, Bs + e2);
        __syncthreads();
        bf16x8 af[4], bfv[4];
#pragma unroll
        for (int r = 0; r < 4; ++r)
            af[r] = ld8(As + (wr + r * 16 + l16) * 32 + quad * 8);
#pragma unroll
        for (int c = 0; c < 4; ++c)
            bfv[c] = ld8(Bs + (wc + c * 16 + l16) * 32 + quad * 8);
#pragma unroll
        for (int r = 0; r < 4; ++r)
#pragma unroll
            for (int c = 0; c < 4; ++c)
                acc[r][c] = mfma16(af[r], bfv[c], acc[r][c]);
        __syncthreads();
    }

    // fragment value (bias+relu+mask), D row = quad*4+reg, col = l16
    float bcol[4];
#pragma unroll
    for (int c = 0; c < 4; ++c) bcol[c] = bias[col0 + wc + c * 16 + l16];

    if constexpr (sizeof(OutT) == 2) {
        // bf16 out: 4 passes x 32 rows; staging stride 136 (bank-friendly)
        bf16* stg = smem;
#pragma unroll
        for (int p = 0; p < 4; ++p) {
            if (wr == (p >> 1) * 64) {
#pragma unroll
                for (int rr = 0; rr < 2; ++rr) {
                    const int r = (p & 1) * 2 + rr;
#pragma unroll
                    for (int c = 0; c < 4; ++c) {
                        const int lcol = wc + c * 16 + l16;
#pragma unroll
                        for (int g = 0; g < 4; ++g) {
                            const int lrow = rr * 16 + quad * 4 + g;
                            const size_t grow = row0 + wr + r * 16 + quad * 4 + g;
                            float v = acc[r][c][g] + bcol[c];
                            v = v > 0.f ? v : 0.f;
                            if (mask) v *= mask[grow];
                            ((unsigned short*)stg)[lrow * 136 + lcol] = f2bs(v);
                        }
                    }
                }
            }
            asm volatile("" ::: "memory");
            __syncthreads();
            const int srow = tid >> 3;            // 0..31
            const int scol = (tid & 7) * 16;      // 0..112
            const us8 o0 = *(const us8*)((unsigned short*)stg + srow * 136 + scol);
            const us8 o1 = *(const us8*)((unsigned short*)stg + srow * 136 + scol + 8);
            OutT* dst = C + (row0 + p * 32 + srow) * ldc + col0 + scol;
            *(us8*)dst = o0;
            *(us8*)(dst + 8) = o1;
            __syncthreads();
        }
    } else {
        // f32 out: 8 passes x 16 rows; staging stride 132 f32
        float* stg = (float*)smem;
#pragma unroll
        for (int p = 0; p < 8; ++p) {
            if (wr == (p >> 2) * 64) {
                const int r = p & 3;
#pragma unroll
                for (int c = 0; c < 4; ++c) {
                    const int lcol = wc + c * 16 + l16;
#pragma unroll
                    for (int g = 0; g < 4; ++g) {
                        const int lrow = quad * 4 + g;
                        const size_t grow = row0 + wr + r * 16 + quad * 4 + g;
                        float v = acc[r][c][g] + bcol[c];
                        v = v > 0.f ? v : 0.f;
                        if (mask) v *= mask[grow];
                        stg[lrow * 132 + lcol] = v;
                    }
                }
            }
            asm volatile("" ::: "memory");
            __syncthreads();
            const int srow = tid >> 4;            // 0..15
            const int scol = (tid & 15) * 8;      // 0..120
            const f32x4 o0 = *(const f32x4*)(stg + srow * 132 + scol);
            const f32x4 o1 = *(const f32x4*)(stg + srow * 132 + scol + 4);
            OutT* dst = C + (row0 + p * 16 + srow) * ldc + col0 + scol;
            *(f32x4*)dst = o0;
            *(f32x4*)(dst + 4) = o1;
            __syncthreads();
        }
    }
}

// ---------------------------------------------------------------------------
// Cross attention. grid.x = Lq/32, grid.y = B*H. 128 thr = 2 waves x 16 q-rows.
// S in registers (16x512/wave), softmax via 16-lane shuffle reduce,
// P LDS round-trip (C-layout -> A-layout).
// R7: K and V staged through a 16KB LDS tile via global_load_lds (zero VGPR,
// async) in m97-style {stage; bar; compute; bar} rounds; both waves share the
// staged data. XOR swizzle (chunk ^= row&7) applied to the GLOBAL source and
// the LDS read (linear gl_lds dest) to kill the 256B/1024B-stride bank
// conflicts. LDS: region A = Qs/Ps union (33.3KB), region B = KV tile (16KB).
__global__ __launch_bounds__(128) void attn_k(
    const bf16* __restrict__ Q, const bf16* __restrict__ Kk,
    const bf16* __restrict__ VT, const float* __restrict__ kmask,
    bf16* __restrict__ Out,
    int Lq, int Lk, int qStride, int kStride, int outStride, int outColOff)
{
    const int bh = blockIdx.y;
    const int b = bh >> 4, h = bh & 15;
    const int n0 = blockIdx.x * 32;
    const int tid = threadIdx.x;
    const int wave = tid >> 6, lane = tid & 63;
    const int l16 = lane & 15, quad = lane >> 4;

    __shared__ __align__(16) bf16 smem[16640 + 8192]; // A: Qs/Ps; B: KV tile
    bf16* kv = smem + 16640;

    // stage Q tile (32 rows x 128 d) into region A
#pragma unroll
    for (int i = 0; i < 4; ++i) {
        const int e = i * 1024 + tid * 8;
        const int r = e >> 7, d = e & 127;
        gl_lds16(Q + (size_t)(b * Lq + n0 + r) * qStride + h * 128 + d, smem + e);
    }
    __syncthreads();

    bf16x8 aq[4];
#pragma unroll
    for (int ks = 0; ks < 4; ++ks)
        aq[ks] = ld8(smem + (wave * 16 + l16) * 128 + ks * 32 + quad * 8);
    __syncthreads();   // union: both waves done reading Qs before Ps overwrites

    // ---- QK^T: 8 rounds of 64 K-rows staged in region B -------------------
    const bf16* Kb = Kk + (size_t)b * Lk * kStride + h * 128;
    f32x4 S[32];
    const int swz = (l16 & 7);
#pragma unroll
    for (int kt = 0; kt < 8; ++kt) {
        // stage: tile [64 rows][128 d]; linear LDS dest, inverse-swz source.
        // per-thread elem e: row r=e>>7, 16B-chunk j=(e>>3)&15 -> src chunk j^(r&7)
#pragma unroll
        for (int c = 0; c < 8; ++c) {
            const int e = c * 1024 + tid * 8;
            const int r = e >> 7;
            const int j = (e >> 3) & 15;
            gl_lds16(Kb + (size_t)(kt * 64 + r) * kStride + ((j ^ (r & 7)) << 3), kv + e);
        }
        __syncthreads();
        __builtin_amdgcn_s_setprio(1);
#pragma unroll
        for (int tt = 0; tt < 4; ++tt) {
            const int row = tt * 16 + l16;
            f32x4 c2 = {0.f, 0.f, 0.f, 0.f};
#pragma unroll
            for (int ks = 0; ks < 4; ++ks)
                c2 = mfma16(aq[ks], ld8(kv + row * 128 + (((ks * 4 + quad) ^ swz) << 3)), c2);
            S[kt * 4 + tt] = c2;
        }
        __builtin_amdgcn_s_setprio(0);
        __syncthreads();
    }

    const float scale = 0.08838834764831845f;  // 1/sqrt(128)
    float mx[4] = {-3.0e38f, -3.0e38f, -3.0e38f, -3.0e38f};
#pragma unroll
    for (int t = 0; t < 32; ++t)
#pragma unroll
        for (int g = 0; g < 4; ++g) mx[g] = fmaxf(mx[g], S[t][g]);
#pragma unroll
    for (int off = 1; off < 16; off <<= 1)
#pragma unroll
        for (int g = 0; g < 4; ++g) mx[g] = fmaxf(mx[g], __shfl_xor(mx[g], off));

    float sm[4] = {0.f, 0.f, 0.f, 0.f};
    const float* mrow = kmask + (size_t)b * Lk;
#pragma unroll
    for (int t = 0; t < 32; ++t) {
        const float mv = mrow[t * 16 + l16];
#pragma unroll
        for (int g = 0; g < 4; ++g) {
            float p = (mv != 0.f) ? __expf((S[t][g] - mx[g]) * scale) : 0.f;
            S[t][g] = p;
            sm[g] += p;
        }
    }
#pragma unroll
    for (int off = 1; off < 16; off <<= 1)
#pragma unroll
        for (int g = 0; g < 4; ++g) sm[g] += __shfl_xor(sm[g], off);
    float rs[4];
#pragma unroll
    for (int g = 0; g < 4; ++g) rs[g] = 1.f / sm[g];

    // P: C-layout regs -> LDS [row16][520] in region A
    bf16* pw = smem + wave * 8320;
#pragma unroll
    for (int t = 0; t < 32; ++t) {
        const int col = t * 16 + l16;
#pragma unroll
        for (int g = 0; g < 4; ++g)
            pw[(quad * 4 + g) * 520 + col] = __float2bfloat16(S[t][g] * rs[g]);
    }
    asm volatile("" ::: "memory");
    __syncthreads();

    bf16x8 pa[16];
#pragma unroll
    for (int ks = 0; ks < 16; ++ks)
        pa[ks] = ld8(pw + l16 * 520 + ks * 32 + quad * 8);

    // ---- PV: 8 rounds of V^T tile [16 d-rows][512 m] staged in region B ---
    const bf16* Vb = VT + (size_t)bh * 128 * Lk;
    const size_t orow = (size_t)b * Lq + n0 + wave * 16 + quad * 4;
    for (int dt = 0; dt < 8; ++dt) {
        // stage: per-thread elem e: row r=e>>9 (512/row), chunk j=(e>>3)&63
#pragma unroll
        for (int c = 0; c < 8; ++c) {
            const int e = c * 1024 + tid * 8;
            const int r = e >> 9;
            const int j = (e >> 3) & 63;
            gl_lds16(Vb + (size_t)(dt * 16 + r) * Lk + ((j ^ (r & 7)) << 3), kv + e);
        }
        __syncthreads();
        __builtin_amdgcn_s_setprio(1);
        f32x4 c2 = {0.f, 0.f, 0.f, 0.f};
#pragma unroll
        for (int ks = 0; ks < 16; ++ks)
            c2 = mfma16(pa[ks], ld8(kv + l16 * 512 + (((ks * 4 + quad) ^ swz) << 3)), c2);
        __builtin_amdgcn_s_setprio(0);
        const int col = outColOff + h * 128 + dt * 16 + l16;
#pragma unroll
        for (int g = 0; g < 4; ++g)
            Out[(orow + g) * outStride + col] = __float2bfloat16(c2[g]);
        __syncthreads();
    }
}

// ---------------------------------------------------------------------------
extern "C" void kernel_launch(void* const* d_in, const int* in_sizes, int n_in,
                              void* d_out, int out_size, void* d_ws, size_t ws_size,
                              hipStream_t stream)
{
    (void)in_sizes; (void)n_in; (void)out_size; (void)ws_size;
    const float* v   = (const float*)d_in[0];
    const float* q   = (const float*)d_in[1];
    const float* vm  = (const float*)d_in[2];
    const float* qm  = (const float*)d_in[3];
    const float* Wv  = (const float*)d_in[4];
    const float* bv  = (const float*)d_in[5];
    const float* Wq  = (const float*)d_in[6];
    const float* bq  = (const float*)d_in[7];
    const float* Wvo = (const float*)d_in[8];
    const float* bvo = (const float*)d_in[9];
    const float* Wqo = (const float*)d_in[10];
    const float* bqo = (const float*)d_in[11];

    float* out_v = (float*)d_out;
    float* out_q = out_v + (size_t)8192 * 2048;

    bf16* ws = (bf16*)d_ws;
    bf16* v_trans = ws; ws += (size_t)8192 * 6144;
    bf16* q_trans = ws; ws += (size_t)8192 * 6144;
    bf16* vcat    = ws; ws += (size_t)8192 * 4096;   // [v(bf16) | v_update]
    bf16* qcat    = ws; ws += (size_t)8192 * 3072;   // [q(bf16) | q_update]
    bf16* WvT     = ws; ws += (size_t)6144 * 2048;
    bf16* WqT     = ws; ws += (size_t)6144 * 1024;
    bf16* WvoT    = ws; ws += (size_t)2048 * 4096;
    bf16* WqoT    = ws; ws += (size_t)2048 * 3072;
    bf16* VvalT   = ws; ws += (size_t)256 * 128 * 512;
    bf16* QvalT   = ws; ws += (size_t)256 * 128 * 512;
    // 432 MiB of d_ws

    // 1) convert inputs to bf16 into concat-left (also the GEMM A operands)
    cvt_cols_k<<<8192, 256, 0, stream>>>(v, vcat, 8, 4096, 8192 * 256);
    cvt_cols_k<<<4096, 256, 0, stream>>>(q, qcat, 7, 3072, 8192 * 128);

    // 2) weight convert+transpose (f32 R x C -> bf16 C x R)
    cvt_transpose_k<<<dim3(96, 32), 256, 0, stream>>>(Wv,  (unsigned short*)WvT,  6144, 2048);
    cvt_transpose_k<<<dim3(96, 16), 256, 0, stream>>>(Wq,  (unsigned short*)WqT,  6144, 1024);
    cvt_transpose_k<<<dim3(32, 64), 256, 0, stream>>>(Wvo, (unsigned short*)WvoT, 2048, 4096);
    cvt_transpose_k<<<dim3(32, 48), 256, 0, stream>>>(Wqo, (unsigned short*)WqoT, 2048, 3072);

    // 3) input projections
    gemm_bt<bf16><<<dim3(48, 64), 256, 0, stream>>>(vcat, WvT, bv, vm, v_trans, 2048, 4096, 2048, 6144);
    gemm_bt<bf16><<<dim3(48, 64), 256, 0, stream>>>(qcat, WqT, bq, qm, q_trans, 1024, 3072, 1024, 6144);

    // 4) value-slice transposes: [b,n,h,d] -> [bh][d][n]
    transpose_k<<<dim3(2, 8, 256), 256, 0, stream>>>((const unsigned short*)(v_trans + 4096), (unsigned short*)VvalT,
                                                     6144, 512, (size_t)512 * 6144, 128, 65536);
    transpose_k<<<dim3(2, 8, 256), 256, 0, stream>>>((const unsigned short*)(q_trans + 4096), (unsigned short*)QvalT,
                                                     6144, 512, (size_t)512 * 6144, 128, 65536);

    // 5) cross attention
    attn_k<<<dim3(16, 256), 128, 0, stream>>>(v_trans + 2048, q_trans, QvalT, qm, vcat,
                                              512, 512, 6144, 6144, 4096, 2048);
    attn_k<<<dim3(16, 256), 128, 0, stream>>>(q_trans + 2048, v_trans, VvalT, vm, qcat,
                                              512, 512, 6144, 6144, 3072, 1024);

    // 6) output projections -> d_out (f32, LDS-staged stores)
    gemm_bt<float><<<dim3(16, 64), 256, 0, stream>>>(vcat, WvoT, bvo, nullptr, out_v, 4096, 4096, 4096, 2048);
    gemm_bt<float><<<dim3(16, 64), 256, 0, stream>>>(qcat, WqoT, bqo, nullptr, out_q, 3072, 3072, 3072, 2048);
}

// Round 4
// 1365.493 us; speedup vs baseline: 1.4961x; 1.1700x over previous
//
#include <hip/hip_runtime.h>
#include <hip/hip_bf16.h>
#include <cstdint>

// InterModalityUpdate — f32 in/out, bf16 MFMA internally (fp32 accum).
// R7: attn K/V LDS-staged via global_load_lds (411us -> <260us each).
// R8: GEMM rewritten: 256x256 tile, BK=32, 8 waves (512 thr), 3-buffer LDS
//     rotation with COUNTED vmcnt(4) at iteration boundaries (loads stay in
//     flight across barriers — removes the m97-structure vmcnt(0) drain that
//     capped MfmaUtil at 25%). 2 phases/iter + setprio (T5). LDS bank
//     swizzle via pre-swizzled global source (rule #21), read XOR folds to
//     per-thread constant. Hazards: WAR safe (stage target held tile t-1,
//     consumed last iteration, barrier-separated); RAW via vmcnt(4)+barrier.
// Dims fixed: B=16 N=M=512 VS=2048 QS=1024 OS=2048 H=16 DH=128.

typedef __hip_bfloat16 bf16;
typedef __attribute__((ext_vector_type(8))) __bf16 bf16x8;
typedef __attribute__((ext_vector_type(4))) float f32x4;
typedef __attribute__((ext_vector_type(4))) unsigned short us4;
typedef __attribute__((ext_vector_type(8))) unsigned short us8;

#define AS1 __attribute__((address_space(1)))
#define AS3 __attribute__((address_space(3)))

__device__ __forceinline__ void gl_lds16(const bf16* g, bf16* l) {
    __builtin_amdgcn_global_load_lds((AS1 void*)(uintptr_t)(g), (AS3 void*)(l), 16, 0, 0);
}

__device__ __forceinline__ bf16x8 ld8(const bf16* p) { return *(const bf16x8*)p; }

__device__ __forceinline__ f32x4 mfma16(bf16x8 a, bf16x8 b, f32x4 c) {
    return __builtin_amdgcn_mfma_f32_16x16x32_bf16(a, b, c, 0, 0, 0);
}

// f32 -> bf16 bits, round-to-nearest-even (finite inputs)
__device__ __forceinline__ unsigned short f2bs(float f) {
    unsigned u = __builtin_bit_cast(unsigned, f);
    unsigned r = u + 0x7FFFu + ((u >> 16) & 1u);
    return (unsigned short)(r >> 16);
}

// ---------------------------------------------------------------------------
// f32 -> bf16 convert into left columns of a wider bf16 matrix. 8 elems/thread.
__global__ __launch_bounds__(256) void cvt_cols_k(
    const float* __restrict__ src, bf16* __restrict__ dst,
    int cprShift, int dstStride, int totalChunks)
{
    const int id = blockIdx.x * 256 + threadIdx.x;
    if (id >= totalChunks) return;
    const int row = id >> cprShift;
    const int cc = (id - (row << cprShift)) << 3;
    const float* s = src + ((size_t)row << (cprShift + 3)) + cc;
    const float4 a = *(const float4*)s;
    const float4 b = *(const float4*)(s + 4);
    us8 o;
    o[0] = f2bs(a.x); o[1] = f2bs(a.y); o[2] = f2bs(a.z); o[3] = f2bs(a.w);
    o[4] = f2bs(b.x); o[5] = f2bs(b.y); o[6] = f2bs(b.z); o[7] = f2bs(b.w);
    *(us8*)(dst + (size_t)row * dstStride + cc) = o;
}

// ---------------------------------------------------------------------------
// Fused convert+transpose for weights. f32 R x C -> bf16 C x R.
__global__ __launch_bounds__(256) void cvt_transpose_k(
    const float* __restrict__ in, unsigned short* __restrict__ out,
    int inStride, int outStride)
{
    __shared__ unsigned short tile[64][65];
    const int ti = blockIdx.x * 64;
    const int tj = blockIdx.y * 64;
    const int t = threadIdx.x;
    const int r = t >> 4;
    const int c4 = (t & 15) << 2;
#pragma unroll
    for (int i = 0; i < 4; ++i) {
        const float4 v = *(const float4*)(in + (size_t)(tj + r + i * 16) * inStride + ti + c4);
        tile[r + i * 16][c4 + 0] = f2bs(v.x);
        tile[r + i * 16][c4 + 1] = f2bs(v.y);
        tile[r + i * 16][c4 + 2] = f2bs(v.z);
        tile[r + i * 16][c4 + 3] = f2bs(v.w);
    }
    __syncthreads();
#pragma unroll
    for (int i = 0; i < 4; ++i) {
        const int orow = ti + r + i * 16;
        us4 v;
        v[0] = tile[c4 + 0][r + i * 16];
        v[1] = tile[c4 + 1][r + i * 16];
        v[2] = tile[c4 + 2][r + i * 16];
        v[3] = tile[c4 + 3][r + i * 16];
        *(us4*)(out + (size_t)orow * outStride + tj + c4) = v;
    }
}

// ---------------------------------------------------------------------------
// bf16 tiled transpose (per-head value slices). grid.z slice offset:
// (z>>4)*inOffB + (z&15)*inOffH.
__global__ __launch_bounds__(256) void transpose_k(
    const unsigned short* __restrict__ in, unsigned short* __restrict__ out,
    int inStride, int outStride, size_t inOffB, int inOffH, size_t outSliceStride)
{
    __shared__ unsigned short tile[64][65];
    const int z = blockIdx.z;
    const unsigned short* inp = in + (size_t)(z >> 4) * inOffB + (size_t)(z & 15) * inOffH;
    unsigned short* outp = out + (size_t)z * outSliceStride;
    const int ti = blockIdx.x * 64;
    const int tj = blockIdx.y * 64;
    const int t = threadIdx.x;
    const int r = t >> 4;
    const int c4 = (t & 15) << 2;
#pragma unroll
    for (int i = 0; i < 4; ++i) {
        us4 v = *(const us4*)(inp + (size_t)(tj + r + i * 16) * inStride + ti + c4);
        tile[r + i * 16][c4 + 0] = v[0];
        tile[r + i * 16][c4 + 1] = v[1];
        tile[r + i * 16][c4 + 2] = v[2];
        tile[r + i * 16][c4 + 3] = v[3];
    }
    __syncthreads();
#pragma unroll
    for (int i = 0; i < 4; ++i) {
        const int orow = ti + r + i * 16;
        us4 v;
        v[0] = tile[c4 + 0][r + i * 16];
        v[1] = tile[c4 + 1][r + i * 16];
        v[2] = tile[c4 + 2][r + i * 16];
        v[3] = tile[c4 + 3][r + i * 16];
        *(us4*)(outp + (size_t)orow * outStride + tj + c4) = v;
    }
}

// ---------------------------------------------------------------------------
// C = relu(A @ B + bias) [* mask[row]]; BT[n][k]. 256x256 tile, BK=32,
// 8 waves (2M x 4N), wave tile 128x64. 3-buffer LDS rotation, counted vmcnt.
// LDS layout per buf: A[256 rows][32 k] then B[256 n-rows][32 k], chunk-
// swizzled: LDS chunk j of row r holds global chunk j ^ ((r>>1)&3).
template <typename OutT>
__global__ __launch_bounds__(512, 2) void gemm_bt(
    const bf16* __restrict__ A, const bf16* __restrict__ BT,
    const float* __restrict__ bias, const float* __restrict__ mask,
    OutT* __restrict__ C, int K, int lda, int ldb, int ldc)
{
    __shared__ __align__(16) bf16 smem[49152];   // 3 x (A 8192 | B 8192) = 96 KB
    const int tid = threadIdx.x;
    const int lane = tid & 63;
    const int l16 = lane & 15;
    const int quad = lane >> 4;
    const int wave = tid >> 6;
    const int wm = wave >> 2;            // 0..1  (row half)
    const int wn = wave & 3;             // 0..3  (col quarter)
    const int rofs = ((quad ^ ((l16 >> 1) & 3)) << 3);  // swizzled read chunk
    const size_t row0 = (size_t)blockIdx.y * 256;
    const size_t col0 = (size_t)blockIdx.x * 256;

    // staging geometry: per buf-half 1024 chunks of 16B; thread owns ci0,ci1
    const int ci0 = tid, ci1 = 512 + tid;
    const int ra0 = ci0 >> 2, ja0 = ci0 & 3;
    const int ra1 = ci1 >> 2, ja1 = ci1 & 3;
    const bf16* Asrc0 = A + (row0 + ra0) * lda + ((ja0 ^ ((ra0 >> 1) & 3)) << 3);
    const bf16* Asrc1 = A + (row0 + ra1) * lda + ((ja1 ^ ((ra1 >> 1) & 3)) << 3);
    const bf16* Bsrc0 = BT + (col0 + ra0) * ldb + ((ja0 ^ ((ra0 >> 1) & 3)) << 3);
    const bf16* Bsrc1 = BT + (col0 + ra1) * ldb + ((ja1 ^ ((ra1 >> 1) & 3)) << 3);

    bf16* b0 = smem;
    bf16* b1 = smem + 16384;
    bf16* b2 = smem + 32768;

    const f32x4 z4 = {0.f, 0.f, 0.f, 0.f};
    f32x4 acc[8][4];
#pragma unroll
    for (int r = 0; r < 8; ++r)
#pragma unroll
        for (int c = 0; c < 4; ++c) acc[r][c] = z4;

    const int nt = K >> 5;

    // prologue: stage tiles 0 and 1; wait tile 0 only (4 newest stay in flight)
    gl_lds16(Asrc0, b0 + ci0 * 8);
    gl_lds16(Asrc1, b0 + ci1 * 8);
    gl_lds16(Bsrc0, b0 + 8192 + ci0 * 8);
    gl_lds16(Bsrc1, b0 + 8192 + ci1 * 8);
    gl_lds16(Asrc0 + 32, b1 + ci0 * 8);
    gl_lds16(Asrc1 + 32, b1 + ci1 * 8);
    gl_lds16(Bsrc0 + 32, b1 + 8192 + ci0 * 8);
    gl_lds16(Bsrc1 + 32, b1 + 8192 + ci1 * 8);
    asm volatile("s_waitcnt vmcnt(4)" ::: "memory");
    __builtin_amdgcn_s_barrier();
    asm volatile("" ::: "memory");

    bf16* cur = b0; bf16* nxt = b1; bf16* nx2 = b2;
    for (int t = 0; t < nt; ++t) {
        const bool st = (t + 2) < nt;
        const int kofs = (t + 2) << 5;
        const bf16* aRd = cur + (wm * 128 + l16) * 32 + rofs;
        const bf16* bRd = cur + 8192 + (wn * 64 + l16) * 32 + rofs;

        // ---- phase 1: stage A(t+2) into nx2; compute frag rows 0-3 ----
        if (st) {
            gl_lds16(Asrc0 + kofs, nx2 + ci0 * 8);
            gl_lds16(Asrc1 + kofs, nx2 + ci1 * 8);
        }
        bf16x8 bfr[4];
#pragma unroll
        for (int fc = 0; fc < 4; ++fc) bfr[fc] = ld8(bRd + fc * 512);
        bf16x8 af[4];
#pragma unroll
        for (int fr = 0; fr < 4; ++fr) af[fr] = ld8(aRd + fr * 512);
        __builtin_amdgcn_s_setprio(1);
#pragma unroll
        for (int fr = 0; fr < 4; ++fr)
#pragma unroll
            for (int fc = 0; fc < 4; ++fc)
                acc[fr][fc] = mfma16(af[fr], bfr[fc], acc[fr][fc]);
        __builtin_amdgcn_s_setprio(0);
        asm volatile("" ::: "memory");
        __builtin_amdgcn_s_barrier();
        asm volatile("" ::: "memory");

        // ---- phase 2: stage B(t+2); compute frag rows 4-7 ----
        if (st) {
            gl_lds16(Bsrc0 + kofs, nx2 + 8192 + ci0 * 8);
            gl_lds16(Bsrc1 + kofs, nx2 + 8192 + ci1 * 8);
        }
#pragma unroll
        for (int fr = 0; fr < 4; ++fr) af[fr] = ld8(aRd + 2048 + fr * 512);
        __builtin_amdgcn_s_setprio(1);
#pragma unroll
        for (int fr = 0; fr < 4; ++fr)
#pragma unroll
            for (int fc = 0; fc < 4; ++fc)
                acc[fr + 4][fc] = mfma16(af[fr], bfr[fc], acc[fr + 4][fc]);
        __builtin_amdgcn_s_setprio(0);

        // ---- boundary: publish tile t+1 (retire its 4 loads; keep t+2's) ----
        if (t + 1 < nt) {
            if (st) asm volatile("s_waitcnt vmcnt(4)" ::: "memory");
            else    asm volatile("s_waitcnt vmcnt(0)" ::: "memory");
            __builtin_amdgcn_s_barrier();
            asm volatile("" ::: "memory");
        }
        bf16* tmp = cur; cur = nxt; nxt = nx2; nx2 = tmp;
    }

    asm volatile("" ::: "memory");
    __syncthreads();   // all waves done with K-loop before smem reuse

    float bcol[4];
#pragma unroll
    for (int fc = 0; fc < 4; ++fc) bcol[fc] = bias[col0 + wn * 64 + fc * 16 + l16];

    if constexpr (sizeof(OutT) == 2) {
        unsigned short* stg = (unsigned short*)smem;   // [32][264]
#pragma unroll
        for (int p = 0; p < 8; ++p) {
            if (wm == (p >> 2)) {
#pragma unroll
                for (int d = 0; d < 2; ++d) {
                    const int fr = (p & 3) * 2 + d;
#pragma unroll
                    for (int fc = 0; fc < 4; ++fc) {
                        const int lcol = wn * 64 + fc * 16 + l16;
#pragma unroll
                        for (int g = 0; g < 4; ++g) {
                            const int lrow = d * 16 + quad * 4 + g;
                            const size_t grow = row0 + (size_t)p * 32 + lrow;
                            float v = acc[fr][fc][g] + bcol[fc];
                            v = v > 0.f ? v : 0.f;
                            if (mask) v *= mask[grow];
                            stg[lrow * 264 + lcol] = f2bs(v);
                        }
                    }
                }
            }
            asm volatile("" ::: "memory");
            __syncthreads();
            const int srow = tid >> 4;            // 0..31
            const int scol = (tid & 15) * 16;     // 0..240
            const us8 o0 = *(const us8*)(stg + srow * 264 + scol);
            const us8 o1 = *(const us8*)(stg + srow * 264 + scol + 8);
            OutT* dst = C + (row0 + p * 32 + srow) * ldc + col0 + scol;
            *(us8*)dst = o0;
            *(us8*)(dst + 8) = o1;
            __syncthreads();
        }
    } else {
        float* stg = (float*)smem;   // [32][260]
#pragma unroll
        for (int p = 0; p < 8; ++p) {
            if (wm == (p >> 2)) {
#pragma unroll
                for (int d = 0; d < 2; ++d) {
                    const int fr = (p & 3) * 2 + d;
#pragma unroll
                    for (int fc = 0; fc < 4; ++fc) {
                        const int lcol = wn * 64 + fc * 16 + l16;
#pragma unroll
                        for (int g = 0; g < 4; ++g) {
                            const int lrow = d * 16 + quad * 4 + g;
                            const size_t grow = row0 + (size_t)p * 32 + lrow;
                            float v = acc[fr][fc][g] + bcol[fc];
                            v = v > 0.f ? v : 0.f;
                            if (mask) v *= mask[grow];
                            stg[lrow * 260 + lcol] = v;
                        }
                    }
                }
            }
            asm volatile("" ::: "memory");
            __syncthreads();
            const int srow = tid >> 4;            // 0..31
            const int scol = (tid & 15) * 16;     // 0..240
            float* dst = (float*)C + (row0 + p * 32 + srow) * ldc + col0 + scol;
            const float* s = stg + srow * 260 + scol;
            *(f32x4*)(dst + 0)  = *(const f32x4*)(s + 0);
            *(f32x4*)(dst + 4)  = *(const f32x4*)(s + 4);
            *(f32x4*)(dst + 8)  = *(const f32x4*)(s + 8);
            *(f32x4*)(dst + 12) = *(const f32x4*)(s + 12);
            __syncthreads();
        }
    }
}

// ---------------------------------------------------------------------------
// Cross attention. grid.x = Lq/32, grid.y = B*H. 128 thr = 2 waves x 16 q-rows.
// K/V staged through 16KB LDS tile via global_load_lds (zero VGPR, async),
// XOR-swizzled source+read (rule #21; linear LDS dest). Unchanged from R7.
__global__ __launch_bounds__(128) void attn_k(
    const bf16* __restrict__ Q, const bf16* __restrict__ Kk,
    const bf16* __restrict__ VT, const float* __restrict__ kmask,
    bf16* __restrict__ Out,
    int Lq, int Lk, int qStride, int kStride, int outStride, int outColOff)
{
    const int bh = blockIdx.y;
    const int b = bh >> 4, h = bh & 15;
    const int n0 = blockIdx.x * 32;
    const int tid = threadIdx.x;
    const int wave = tid >> 6, lane = tid & 63;
    const int l16 = lane & 15, quad = lane >> 4;

    __shared__ __align__(16) bf16 smem[16640 + 8192]; // A: Qs/Ps; B: KV tile
    bf16* kv = smem + 16640;

    // stage Q tile (32 rows x 128 d) into region A
#pragma unroll
    for (int i = 0; i < 4; ++i) {
        const int e = i * 1024 + tid * 8;
        const int r = e >> 7, d = e & 127;
        gl_lds16(Q + (size_t)(b * Lq + n0 + r) * qStride + h * 128 + d, smem + e);
    }
    __syncthreads();

    bf16x8 aq[4];
#pragma unroll
    for (int ks = 0; ks < 4; ++ks)
        aq[ks] = ld8(smem + (wave * 16 + l16) * 128 + ks * 32 + quad * 8);
    __syncthreads();   // union: both waves done reading Qs before Ps overwrites

    // ---- QK^T: 8 rounds of 64 K-rows staged in region B -------------------
    const bf16* Kb = Kk + (size_t)b * Lk * kStride + h * 128;
    f32x4 S[32];
    const int swz = (l16 & 7);
#pragma unroll
    for (int kt = 0; kt < 8; ++kt) {
#pragma unroll
        for (int c = 0; c < 8; ++c) {
            const int e = c * 1024 + tid * 8;
            const int r = e >> 7;
            const int j = (e >> 3) & 15;
            gl_lds16(Kb + (size_t)(kt * 64 + r) * kStride + ((j ^ (r & 7)) << 3), kv + e);
        }
        __syncthreads();
        __builtin_amdgcn_s_setprio(1);
#pragma unroll
        for (int tt = 0; tt < 4; ++tt) {
            const int row = tt * 16 + l16;
            f32x4 c2 = {0.f, 0.f, 0.f, 0.f};
#pragma unroll
            for (int ks = 0; ks < 4; ++ks)
                c2 = mfma16(aq[ks], ld8(kv + row * 128 + (((ks * 4 + quad) ^ swz) << 3)), c2);
            S[kt * 4 + tt] = c2;
        }
        __builtin_amdgcn_s_setprio(0);
        __syncthreads();
    }

    const float scale = 0.08838834764831845f;  // 1/sqrt(128)
    float mx[4] = {-3.0e38f, -3.0e38f, -3.0e38f, -3.0e38f};
#pragma unroll
    for (int t = 0; t < 32; ++t)
#pragma unroll
        for (int g = 0; g < 4; ++g) mx[g] = fmaxf(mx[g], S[t][g]);
#pragma unroll
    for (int off = 1; off < 16; off <<= 1)
#pragma unroll
        for (int g = 0; g < 4; ++g) mx[g] = fmaxf(mx[g], __shfl_xor(mx[g], off));

    float sm[4] = {0.f, 0.f, 0.f, 0.f};
    const float* mrow = kmask + (size_t)b * Lk;
#pragma unroll
    for (int t = 0; t < 32; ++t) {
        const float mv = mrow[t * 16 + l16];
#pragma unroll
        for (int g = 0; g < 4; ++g) {
            float p = (mv != 0.f) ? __expf((S[t][g] - mx[g]) * scale) : 0.f;
            S[t][g] = p;
            sm[g] += p;
        }
    }
#pragma unroll
    for (int off = 1; off < 16; off <<= 1)
#pragma unroll
        for (int g = 0; g < 4; ++g) sm[g] += __shfl_xor(sm[g], off);
    float rs[4];
#pragma unroll
    for (int g = 0; g < 4; ++g) rs[g] = 1.f / sm[g];

    // P: C-layout regs -> LDS [row16][520] in region A
    bf16* pw = smem + wave * 8320;
#pragma unroll
    for (int t = 0; t < 32; ++t) {
        const int col = t * 16 + l16;
#pragma unroll
        for (int g = 0; g < 4; ++g)
            pw[(quad * 4 + g) * 520 + col] = __float2bfloat16(S[t][g] * rs[g]);
    }
    asm volatile("" ::: "memory");
    __syncthreads();

    bf16x8 pa[16];
#pragma unroll
    for (int ks = 0; ks < 16; ++ks)
        pa[ks] = ld8(pw + l16 * 520 + ks * 32 + quad * 8);

    // ---- PV: 8 rounds of V^T tile [16 d-rows][512 m] staged in region B ---
    const bf16* Vb = VT + (size_t)bh * 128 * Lk;
    const size_t orow = (size_t)b * Lq + n0 + wave * 16 + quad * 4;
    for (int dt = 0; dt < 8; ++dt) {
#pragma unroll
        for (int c = 0; c < 8; ++c) {
            const int e = c * 1024 + tid * 8;
            const int r = e >> 9;
            const int j = (e >> 3) & 63;
            gl_lds16(Vb + (size_t)(dt * 16 + r) * Lk + ((j ^ (r & 7)) << 3), kv + e);
        }
        __syncthreads();
        __builtin_amdgcn_s_setprio(1);
        f32x4 c2 = {0.f, 0.f, 0.f, 0.f};
#pragma unroll
        for (int ks = 0; ks < 16; ++ks)
            c2 = mfma16(pa[ks], ld8(kv + l16 * 512 + (((ks * 4 + quad) ^ swz) << 3)), c2);
        __builtin_amdgcn_s_setprio(0);
        const int col = outColOff + h * 128 + dt * 16 + l16;
#pragma unroll
        for (int g = 0; g < 4; ++g)
            Out[(orow + g) * outStride + col] = __float2bfloat16(c2[g]);
        __syncthreads();
    }
}

// ---------------------------------------------------------------------------
extern "C" void kernel_launch(void* const* d_in, const int* in_sizes, int n_in,
                              void* d_out, int out_size, void* d_ws, size_t ws_size,
                              hipStream_t stream)
{
    (void)in_sizes; (void)n_in; (void)out_size; (void)ws_size;
    const float* v   = (const float*)d_in[0];
    const float* q   = (const float*)d_in[1];
    const float* vm  = (const float*)d_in[2];
    const float* qm  = (const float*)d_in[3];
    const float* Wv  = (const float*)d_in[4];
    const float* bv  = (const float*)d_in[5];
    const float* Wq  = (const float*)d_in[6];
    const float* bq  = (const float*)d_in[7];
    const float* Wvo = (const float*)d_in[8];
    const float* bvo = (const float*)d_in[9];
    const float* Wqo = (const float*)d_in[10];
    const float* bqo = (const float*)d_in[11];

    float* out_v = (float*)d_out;
    float* out_q = out_v + (size_t)8192 * 2048;

    bf16* ws = (bf16*)d_ws;
    bf16* v_trans = ws; ws += (size_t)8192 * 6144;
    bf16* q_trans = ws; ws += (size_t)8192 * 6144;
    bf16* vcat    = ws; ws += (size_t)8192 * 4096;   // [v(bf16) | v_update]
    bf16* qcat    = ws; ws += (size_t)8192 * 3072;   // [q(bf16) | q_update]
    bf16* WvT     = ws; ws += (size_t)6144 * 2048;
    bf16* WqT     = ws; ws += (size_t)6144 * 1024;
    bf16* WvoT    = ws; ws += (size_t)2048 * 4096;
    bf16* WqoT    = ws; ws += (size_t)2048 * 3072;
    bf16* VvalT   = ws; ws += (size_t)256 * 128 * 512;
    bf16* QvalT   = ws; ws += (size_t)256 * 128 * 512;
    // 432 MiB of d_ws

    // 1) convert inputs to bf16 into concat-left (also the GEMM A operands)
    cvt_cols_k<<<8192, 256, 0, stream>>>(v, vcat, 8, 4096, 8192 * 256);
    cvt_cols_k<<<4096, 256, 0, stream>>>(q, qcat, 7, 3072, 8192 * 128);

    // 2) weight convert+transpose (f32 R x C -> bf16 C x R)
    cvt_transpose_k<<<dim3(96, 32), 256, 0, stream>>>(Wv,  (unsigned short*)WvT,  6144, 2048);
    cvt_transpose_k<<<dim3(96, 16), 256, 0, stream>>>(Wq,  (unsigned short*)WqT,  6144, 1024);
    cvt_transpose_k<<<dim3(32, 64), 256, 0, stream>>>(Wvo, (unsigned short*)WvoT, 2048, 4096);
    cvt_transpose_k<<<dim3(32, 48), 256, 0, stream>>>(Wqo, (unsigned short*)WqoT, 2048, 3072);

    // 3) input projections (256x256 tiles)
    gemm_bt<bf16><<<dim3(24, 32), 512, 0, stream>>>(vcat, WvT, bv, vm, v_trans, 2048, 4096, 2048, 6144);
    gemm_bt<bf16><<<dim3(24, 32), 512, 0, stream>>>(qcat, WqT, bq, qm, q_trans, 1024, 3072, 1024, 6144);

    // 4) value-slice transposes: [b,n,h,d] -> [bh][d][n]
    transpose_k<<<dim3(2, 8, 256), 256, 0, stream>>>((const unsigned short*)(v_trans + 4096), (unsigned short*)VvalT,
                                                     6144, 512, (size_t)512 * 6144, 128, 65536);
    transpose_k<<<dim3(2, 8, 256), 256, 0, stream>>>((const unsigned short*)(q_trans + 4096), (unsigned short*)QvalT,
                                                     6144, 512, (size_t)512 * 6144, 128, 65536);

    // 5) cross attention
    attn_k<<<dim3(16, 256), 128, 0, stream>>>(v_trans + 2048, q_trans, QvalT, qm, vcat,
                                              512, 512, 6144, 6144, 4096, 2048);
    attn_k<<<dim3(16, 256), 128, 0, stream>>>(q_trans + 2048, v_trans, VvalT, vm, qcat,
                                              512, 512, 6144, 6144, 3072, 1024);

    // 6) output projections -> d_out (f32, LDS-staged stores)
    gemm_bt<float><<<dim3(8, 32), 512, 0, stream>>>(vcat, WvoT, bvo, nullptr, out_v, 4096, 4096, 4096, 2048);
    gemm_bt<float><<<dim3(8, 32), 512, 0, stream>>>(qcat, WqoT, bqo, nullptr, out_q, 3072, 3072, 3072, 2048);
}

// Round 5
// 1351.816 us; speedup vs baseline: 1.5112x; 1.0101x over previous
//
#include <hip/hip_runtime.h>
#include <hip/hip_bf16.h>
#include <cstdint>

// InterModalityUpdate — f32 in/out, bf16 MFMA internally (fp32 accum).
// R7: attn K/V LDS-staged via global_load_lds (411us -> ~250us each).
// R8: GEMM 256x256/BK=32/8-wave, 3-buffer rotation, counted vmcnt(4),
//     source-swizzled LDS (bank conflicts 25.6M -> 0). 352 -> 273us.
// R9: removed the mid-iteration barrier (protected nothing: staged buffer has
//     no readers in-iteration, cur is stable) and fused each iteration into
//     one free-running region: 12 ds_reads (consumption order) + 4 stages +
//     32 MFMA, then the proven boundary vmcnt(4)+s_barrier. Waves now drift
//     within the iteration so reads of one wave overlap MFMAs of another —
//     attacks the measured 3410cyc/iter vs ~1400cyc ideal (MfmaUtil 33%).
// Dims fixed: B=16 N=M=512 VS=2048 QS=1024 OS=2048 H=16 DH=128.

typedef __hip_bfloat16 bf16;
typedef __attribute__((ext_vector_type(8))) __bf16 bf16x8;
typedef __attribute__((ext_vector_type(4))) float f32x4;
typedef __attribute__((ext_vector_type(4))) unsigned short us4;
typedef __attribute__((ext_vector_type(8))) unsigned short us8;

#define AS1 __attribute__((address_space(1)))
#define AS3 __attribute__((address_space(3)))

__device__ __forceinline__ void gl_lds16(const bf16* g, bf16* l) {
    __builtin_amdgcn_global_load_lds((AS1 void*)(uintptr_t)(g), (AS3 void*)(l), 16, 0, 0);
}

__device__ __forceinline__ bf16x8 ld8(const bf16* p) { return *(const bf16x8*)p; }

__device__ __forceinline__ f32x4 mfma16(bf16x8 a, bf16x8 b, f32x4 c) {
    return __builtin_amdgcn_mfma_f32_16x16x32_bf16(a, b, c, 0, 0, 0);
}

// f32 -> bf16 bits, round-to-nearest-even (finite inputs)
__device__ __forceinline__ unsigned short f2bs(float f) {
    unsigned u = __builtin_bit_cast(unsigned, f);
    unsigned r = u + 0x7FFFu + ((u >> 16) & 1u);
    return (unsigned short)(r >> 16);
}

// ---------------------------------------------------------------------------
// f32 -> bf16 convert into left columns of a wider bf16 matrix. 8 elems/thread.
__global__ __launch_bounds__(256) void cvt_cols_k(
    const float* __restrict__ src, bf16* __restrict__ dst,
    int cprShift, int dstStride, int totalChunks)
{
    const int id = blockIdx.x * 256 + threadIdx.x;
    if (id >= totalChunks) return;
    const int row = id >> cprShift;
    const int cc = (id - (row << cprShift)) << 3;
    const float* s = src + ((size_t)row << (cprShift + 3)) + cc;
    const float4 a = *(const float4*)s;
    const float4 b = *(const float4*)(s + 4);
    us8 o;
    o[0] = f2bs(a.x); o[1] = f2bs(a.y); o[2] = f2bs(a.z); o[3] = f2bs(a.w);
    o[4] = f2bs(b.x); o[5] = f2bs(b.y); o[6] = f2bs(b.z); o[7] = f2bs(b.w);
    *(us8*)(dst + (size_t)row * dstStride + cc) = o;
}

// ---------------------------------------------------------------------------
// Fused convert+transpose for weights. f32 R x C -> bf16 C x R.
__global__ __launch_bounds__(256) void cvt_transpose_k(
    const float* __restrict__ in, unsigned short* __restrict__ out,
    int inStride, int outStride)
{
    __shared__ unsigned short tile[64][65];
    const int ti = blockIdx.x * 64;
    const int tj = blockIdx.y * 64;
    const int t = threadIdx.x;
    const int r = t >> 4;
    const int c4 = (t & 15) << 2;
#pragma unroll
    for (int i = 0; i < 4; ++i) {
        const float4 v = *(const float4*)(in + (size_t)(tj + r + i * 16) * inStride + ti + c4);
        tile[r + i * 16][c4 + 0] = f2bs(v.x);
        tile[r + i * 16][c4 + 1] = f2bs(v.y);
        tile[r + i * 16][c4 + 2] = f2bs(v.z);
        tile[r + i * 16][c4 + 3] = f2bs(v.w);
    }
    __syncthreads();
#pragma unroll
    for (int i = 0; i < 4; ++i) {
        const int orow = ti + r + i * 16;
        us4 v;
        v[0] = tile[c4 + 0][r + i * 16];
        v[1] = tile[c4 + 1][r + i * 16];
        v[2] = tile[c4 + 2][r + i * 16];
        v[3] = tile[c4 + 3][r + i * 16];
        *(us4*)(out + (size_t)orow * outStride + tj + c4) = v;
    }
}

// ---------------------------------------------------------------------------
// bf16 tiled transpose (per-head value slices). grid.z slice offset:
// (z>>4)*inOffB + (z&15)*inOffH.
__global__ __launch_bounds__(256) void transpose_k(
    const unsigned short* __restrict__ in, unsigned short* __restrict__ out,
    int inStride, int outStride, size_t inOffB, int inOffH, size_t outSliceStride)
{
    __shared__ unsigned short tile[64][65];
    const int z = blockIdx.z;
    const unsigned short* inp = in + (size_t)(z >> 4) * inOffB + (size_t)(z & 15) * inOffH;
    unsigned short* outp = out + (size_t)z * outSliceStride;
    const int ti = blockIdx.x * 64;
    const int tj = blockIdx.y * 64;
    const int t = threadIdx.x;
    const int r = t >> 4;
    const int c4 = (t & 15) << 2;
#pragma unroll
    for (int i = 0; i < 4; ++i) {
        us4 v = *(const us4*)(inp + (size_t)(tj + r + i * 16) * inStride + ti + c4);
        tile[r + i * 16][c4 + 0] = v[0];
        tile[r + i * 16][c4 + 1] = v[1];
        tile[r + i * 16][c4 + 2] = v[2];
        tile[r + i * 16][c4 + 3] = v[3];
    }
    __syncthreads();
#pragma unroll
    for (int i = 0; i < 4; ++i) {
        const int orow = ti + r + i * 16;
        us4 v;
        v[0] = tile[c4 + 0][r + i * 16];
        v[1] = tile[c4 + 1][r + i * 16];
        v[2] = tile[c4 + 2][r + i * 16];
        v[3] = tile[c4 + 3][r + i * 16];
        *(us4*)(outp + (size_t)orow * outStride + tj + c4) = v;
    }
}

// ---------------------------------------------------------------------------
// C = relu(A @ B + bias) [* mask[row]]; BT[n][k]. 256x256 tile, BK=32,
// 8 waves (2M x 4N), wave tile 128x64. 3-buffer LDS rotation, counted vmcnt,
// ONE barrier per K-iter. LDS chunk-swizzle: chunk j of row r holds global
// chunk j ^ ((r>>1)&3) (source-side; read XOR folds to per-thread constant).
// Hazards: WAR — every ds_read result feeds an MFMA this iter, so all reads
// retire before the wave's barrier arrival; post-barrier stages only touch
// the buffer consumed last iter. RAW — boundary vmcnt(4) retires tile t+1's
// 4 loads (oldest) while keeping tile t+2's 4 in flight.
template <typename OutT>
__global__ __launch_bounds__(512, 2) void gemm_bt(
    const bf16* __restrict__ A, const bf16* __restrict__ BT,
    const float* __restrict__ bias, const float* __restrict__ mask,
    OutT* __restrict__ C, int K, int lda, int ldb, int ldc)
{
    __shared__ __align__(16) bf16 smem[49152];   // 3 x (A 8192 | B 8192) = 96 KB
    const int tid = threadIdx.x;
    const int lane = tid & 63;
    const int l16 = lane & 15;
    const int quad = lane >> 4;
    const int wave = tid >> 6;
    const int wm = wave >> 2;            // 0..1  (row half)
    const int wn = wave & 3;             // 0..3  (col quarter)
    const int rofs = ((quad ^ ((l16 >> 1) & 3)) << 3);  // swizzled read chunk
    const size_t row0 = (size_t)blockIdx.y * 256;
    const size_t col0 = (size_t)blockIdx.x * 256;

    // staging geometry: per buf-half 1024 chunks of 16B; thread owns ci0,ci1
    const int ci0 = tid, ci1 = 512 + tid;
    const int ra0 = ci0 >> 2, ja0 = ci0 & 3;
    const int ra1 = ci1 >> 2, ja1 = ci1 & 3;
    const bf16* Asrc0 = A + (row0 + ra0) * lda + ((ja0 ^ ((ra0 >> 1) & 3)) << 3);
    const bf16* Asrc1 = A + (row0 + ra1) * lda + ((ja1 ^ ((ra1 >> 1) & 3)) << 3);
    const bf16* Bsrc0 = BT + (col0 + ra0) * ldb + ((ja0 ^ ((ra0 >> 1) & 3)) << 3);
    const bf16* Bsrc1 = BT + (col0 + ra1) * ldb + ((ja1 ^ ((ra1 >> 1) & 3)) << 3);

    bf16* b0 = smem;
    bf16* b1 = smem + 16384;
    bf16* b2 = smem + 32768;

    const f32x4 z4 = {0.f, 0.f, 0.f, 0.f};
    f32x4 acc[8][4];
#pragma unroll
    for (int r = 0; r < 8; ++r)
#pragma unroll
        for (int c = 0; c < 4; ++c) acc[r][c] = z4;

    const int nt = K >> 5;

    // prologue: stage tiles 0 and 1; wait tile 0 only (4 newest stay in flight)
    gl_lds16(Asrc0, b0 + ci0 * 8);
    gl_lds16(Asrc1, b0 + ci1 * 8);
    gl_lds16(Bsrc0, b0 + 8192 + ci0 * 8);
    gl_lds16(Bsrc1, b0 + 8192 + ci1 * 8);
    gl_lds16(Asrc0 + 32, b1 + ci0 * 8);
    gl_lds16(Asrc1 + 32, b1 + ci1 * 8);
    gl_lds16(Bsrc0 + 32, b1 + 8192 + ci0 * 8);
    gl_lds16(Bsrc1 + 32, b1 + 8192 + ci1 * 8);
    asm volatile("s_waitcnt vmcnt(4)" ::: "memory");
    __builtin_amdgcn_s_barrier();
    asm volatile("" ::: "memory");

    bf16* cur = b0; bf16* nxt = b1; bf16* nx2 = b2;
    for (int t = 0; t < nt; ++t) {
        const bool st = (t + 2) < nt;
        const int kofs = (t + 2) << 5;
        const bf16* aRd = cur + (wm * 128 + l16) * 32 + rofs;
        const bf16* bRd = cur + 8192 + (wn * 64 + l16) * 32 + rofs;

        // issue all 12 LDS reads in consumption order (fine-grained lgkmcnt
        // lets the first MFMAs start after the first 8 retire)
        bf16x8 bfr[4], af[4], af2[4];
#pragma unroll
        for (int fc = 0; fc < 4; ++fc) bfr[fc] = ld8(bRd + fc * 512);
#pragma unroll
        for (int fr = 0; fr < 4; ++fr) af[fr] = ld8(aRd + fr * 512);
#pragma unroll
        for (int fr = 0; fr < 4; ++fr) af2[fr] = ld8(aRd + 2048 + fr * 512);

        // stage tile t+2 (A and B halves) into the buffer freed last iter
        if (st) {
            gl_lds16(Asrc0 + kofs, nx2 + ci0 * 8);
            gl_lds16(Asrc1 + kofs, nx2 + ci1 * 8);
            gl_lds16(Bsrc0 + kofs, nx2 + 8192 + ci0 * 8);
            gl_lds16(Bsrc1 + kofs, nx2 + 8192 + ci1 * 8);
        }

        __builtin_amdgcn_s_setprio(1);
#pragma unroll
        for (int fr = 0; fr < 4; ++fr)
#pragma unroll
            for (int fc = 0; fc < 4; ++fc)
                acc[fr][fc] = mfma16(af[fr], bfr[fc], acc[fr][fc]);
#pragma unroll
        for (int fr = 0; fr < 4; ++fr)
#pragma unroll
            for (int fc = 0; fc < 4; ++fc)
                acc[fr + 4][fc] = mfma16(af2[fr], bfr[fc], acc[fr + 4][fc]);
        __builtin_amdgcn_s_setprio(0);

        // boundary: publish tile t+1 (retire its 4 loads; keep t+2's in flight)
        if (t + 1 < nt) {
            if (st) asm volatile("s_waitcnt vmcnt(4)" ::: "memory");
            else    asm volatile("s_waitcnt vmcnt(0)" ::: "memory");
            __builtin_amdgcn_s_barrier();
            asm volatile("" ::: "memory");
        }
        bf16* tmp = cur; cur = nxt; nxt = nx2; nx2 = tmp;
    }

    asm volatile("" ::: "memory");
    __syncthreads();   // all waves done with K-loop before smem reuse

    float bcol[4];
#pragma unroll
    for (int fc = 0; fc < 4; ++fc) bcol[fc] = bias[col0 + wn * 64 + fc * 16 + l16];

    if constexpr (sizeof(OutT) == 2) {
        unsigned short* stg = (unsigned short*)smem;   // [32][264]
#pragma unroll
        for (int p = 0; p < 8; ++p) {
            if (wm == (p >> 2)) {
#pragma unroll
                for (int d = 0; d < 2; ++d) {
                    const int fr = (p & 3) * 2 + d;
#pragma unroll
                    for (int fc = 0; fc < 4; ++fc) {
                        const int lcol = wn * 64 + fc * 16 + l16;
#pragma unroll
                        for (int g = 0; g < 4; ++g) {
                            const int lrow = d * 16 + quad * 4 + g;
                            const size_t grow = row0 + (size_t)p * 32 + lrow;
                            float v = acc[fr][fc][g] + bcol[fc];
                            v = v > 0.f ? v : 0.f;
                            if (mask) v *= mask[grow];
                            stg[lrow * 264 + lcol] = f2bs(v);
                        }
                    }
                }
            }
            asm volatile("" ::: "memory");
            __syncthreads();
            const int srow = tid >> 4;            // 0..31
            const int scol = (tid & 15) * 16;     // 0..240
            const us8 o0 = *(const us8*)(stg + srow * 264 + scol);
            const us8 o1 = *(const us8*)(stg + srow * 264 + scol + 8);
            OutT* dst = C + (row0 + p * 32 + srow) * ldc + col0 + scol;
            *(us8*)dst = o0;
            *(us8*)(dst + 8) = o1;
            __syncthreads();
        }
    } else {
        float* stg = (float*)smem;   // [32][260]
#pragma unroll
        for (int p = 0; p < 8; ++p) {
            if (wm == (p >> 2)) {
#pragma unroll
                for (int d = 0; d < 2; ++d) {
                    const int fr = (p & 3) * 2 + d;
#pragma unroll
                    for (int fc = 0; fc < 4; ++fc) {
                        const int lcol = wn * 64 + fc * 16 + l16;
#pragma unroll
                        for (int g = 0; g < 4; ++g) {
                            const int lrow = d * 16 + quad * 4 + g;
                            const size_t grow = row0 + (size_t)p * 32 + lrow;
                            float v = acc[fr][fc][g] + bcol[fc];
                            v = v > 0.f ? v : 0.f;
                            if (mask) v *= mask[grow];
                            stg[lrow * 260 + lcol] = v;
                        }
                    }
                }
            }
            asm volatile("" ::: "memory");
            __syncthreads();
            const int srow = tid >> 4;            // 0..31
            const int scol = (tid & 15) * 16;     // 0..240
            float* dst = (float*)C + (row0 + p * 32 + srow) * ldc + col0 + scol;
            const float* s = stg + srow * 260 + scol;
            *(f32x4*)(dst + 0)  = *(const f32x4*)(s + 0);
            *(f32x4*)(dst + 4)  = *(const f32x4*)(s + 4);
            *(f32x4*)(dst + 8)  = *(const f32x4*)(s + 8);
            *(f32x4*)(dst + 12) = *(const f32x4*)(s + 12);
            __syncthreads();
        }
    }
}

// ---------------------------------------------------------------------------
// Cross attention. grid.x = Lq/32, grid.y = B*H. 128 thr = 2 waves x 16 q-rows.
// K/V staged through 16KB LDS tile via global_load_lds (zero VGPR, async),
// XOR-swizzled source+read (rule #21; linear LDS dest). Unchanged from R8.
__global__ __launch_bounds__(128) void attn_k(
    const bf16* __restrict__ Q, const bf16* __restrict__ Kk,
    const bf16* __restrict__ VT, const float* __restrict__ kmask,
    bf16* __restrict__ Out,
    int Lq, int Lk, int qStride, int kStride, int outStride, int outColOff)
{
    const int bh = blockIdx.y;
    const int b = bh >> 4, h = bh & 15;
    const int n0 = blockIdx.x * 32;
    const int tid = threadIdx.x;
    const int wave = tid >> 6, lane = tid & 63;
    const int l16 = lane & 15, quad = lane >> 4;

    __shared__ __align__(16) bf16 smem[16640 + 8192]; // A: Qs/Ps; B: KV tile
    bf16* kv = smem + 16640;

    // stage Q tile (32 rows x 128 d) into region A
#pragma unroll
    for (int i = 0; i < 4; ++i) {
        const int e = i * 1024 + tid * 8;
        const int r = e >> 7, d = e & 127;
        gl_lds16(Q + (size_t)(b * Lq + n0 + r) * qStride + h * 128 + d, smem + e);
    }
    __syncthreads();

    bf16x8 aq[4];
#pragma unroll
    for (int ks = 0; ks < 4; ++ks)
        aq[ks] = ld8(smem + (wave * 16 + l16) * 128 + ks * 32 + quad * 8);
    __syncthreads();   // union: both waves done reading Qs before Ps overwrites

    // ---- QK^T: 8 rounds of 64 K-rows staged in region B -------------------
    const bf16* Kb = Kk + (size_t)b * Lk * kStride + h * 128;
    f32x4 S[32];
    const int swz = (l16 & 7);
#pragma unroll
    for (int kt = 0; kt < 8; ++kt) {
#pragma unroll
        for (int c = 0; c < 8; ++c) {
            const int e = c * 1024 + tid * 8;
            const int r = e >> 7;
            const int j = (e >> 3) & 15;
            gl_lds16(Kb + (size_t)(kt * 64 + r) * kStride + ((j ^ (r & 7)) << 3), kv + e);
        }
        __syncthreads();
        __builtin_amdgcn_s_setprio(1);
#pragma unroll
        for (int tt = 0; tt < 4; ++tt) {
            const int row = tt * 16 + l16;
            f32x4 c2 = {0.f, 0.f, 0.f, 0.f};
#pragma unroll
            for (int ks = 0; ks < 4; ++ks)
                c2 = mfma16(aq[ks], ld8(kv + row * 128 + (((ks * 4 + quad) ^ swz) << 3)), c2);
            S[kt * 4 + tt] = c2;
        }
        __builtin_amdgcn_s_setprio(0);
        __syncthreads();
    }

    const float scale = 0.08838834764831845f;  // 1/sqrt(128)
    float mx[4] = {-3.0e38f, -3.0e38f, -3.0e38f, -3.0e38f};
#pragma unroll
    for (int t = 0; t < 32; ++t)
#pragma unroll
        for (int g = 0; g < 4; ++g) mx[g] = fmaxf(mx[g], S[t][g]);
#pragma unroll
    for (int off = 1; off < 16; off <<= 1)
#pragma unroll
        for (int g = 0; g < 4; ++g) mx[g] = fmaxf(mx[g], __shfl_xor(mx[g], off));

    float sm[4] = {0.f, 0.f, 0.f, 0.f};
    const float* mrow = kmask + (size_t)b * Lk;
#pragma unroll
    for (int t = 0; t < 32; ++t) {
        const float mv = mrow[t * 16 + l16];
#pragma unroll
        for (int g = 0; g < 4; ++g) {
            float p = (mv != 0.f) ? __expf((S[t][g] - mx[g]) * scale) : 0.f;
            S[t][g] = p;
            sm[g] += p;
        }
    }
#pragma unroll
    for (int off = 1; off < 16; off <<= 1)
#pragma unroll
        for (int g = 0; g < 4; ++g) sm[g] += __shfl_xor(sm[g], off);
    float rs[4];
#pragma unroll
    for (int g = 0; g < 4; ++g) rs[g] = 1.f / sm[g];

    // P: C-layout regs -> LDS [row16][520] in region A
    bf16* pw = smem + wave * 8320;
#pragma unroll
    for (int t = 0; t < 32; ++t) {
        const int col = t * 16 + l16;
#pragma unroll
        for (int g = 0; g < 4; ++g)
            pw[(quad * 4 + g) * 520 + col] = __float2bfloat16(S[t][g] * rs[g]);
    }
    asm volatile("" ::: "memory");
    __syncthreads();

    bf16x8 pa[16];
#pragma unroll
    for (int ks = 0; ks < 16; ++ks)
        pa[ks] = ld8(pw + l16 * 520 + ks * 32 + quad * 8);

    // ---- PV: 8 rounds of V^T tile [16 d-rows][512 m] staged in region B ---
    const bf16* Vb = VT + (size_t)bh * 128 * Lk;
    const size_t orow = (size_t)b * Lq + n0 + wave * 16 + quad * 4;
    for (int dt = 0; dt < 8; ++dt) {
#pragma unroll
        for (int c = 0; c < 8; ++c) {
            const int e = c * 1024 + tid * 8;
            const int r = e >> 9;
            const int j = (e >> 3) & 63;
            gl_lds16(Vb + (size_t)(dt * 16 + r) * Lk + ((j ^ (r & 7)) << 3), kv + e);
        }
        __syncthreads();
        __builtin_amdgcn_s_setprio(1);
        f32x4 c2 = {0.f, 0.f, 0.f, 0.f};
#pragma unroll
        for (int ks = 0; ks < 16; ++ks)
            c2 = mfma16(pa[ks], ld8(kv + l16 * 512 + (((ks * 4 + quad) ^ swz) << 3)), c2);
        __builtin_amdgcn_s_setprio(0);
        const int col = outColOff + h * 128 + dt * 16 + l16;
#pragma unroll
        for (int g = 0; g < 4; ++g)
            Out[(orow + g) * outStride + col] = __float2bfloat16(c2[g]);
        __syncthreads();
    }
}

// ---------------------------------------------------------------------------
extern "C" void kernel_launch(void* const* d_in, const int* in_sizes, int n_in,
                              void* d_out, int out_size, void* d_ws, size_t ws_size,
                              hipStream_t stream)
{
    (void)in_sizes; (void)n_in; (void)out_size; (void)ws_size;
    const float* v   = (const float*)d_in[0];
    const float* q   = (const float*)d_in[1];
    const float* vm  = (const float*)d_in[2];
    const float* qm  = (const float*)d_in[3];
    const float* Wv  = (const float*)d_in[4];
    const float* bv  = (const float*)d_in[5];
    const float* Wq  = (const float*)d_in[6];
    const float* bq  = (const float*)d_in[7];
    const float* Wvo = (const float*)d_in[8];
    const float* bvo = (const float*)d_in[9];
    const float* Wqo = (const float*)d_in[10];
    const float* bqo = (const float*)d_in[11];

    float* out_v = (float*)d_out;
    float* out_q = out_v + (size_t)8192 * 2048;

    bf16* ws = (bf16*)d_ws;
    bf16* v_trans = ws; ws += (size_t)8192 * 6144;
    bf16* q_trans = ws; ws += (size_t)8192 * 6144;
    bf16* vcat    = ws; ws += (size_t)8192 * 4096;   // [v(bf16) | v_update]
    bf16* qcat    = ws; ws += (size_t)8192 * 3072;   // [q(bf16) | q_update]
    bf16* WvT     = ws; ws += (size_t)6144 * 2048;
    bf16* WqT     = ws; ws += (size_t)6144 * 1024;
    bf16* WvoT    = ws; ws += (size_t)2048 * 4096;
    bf16* WqoT    = ws; ws += (size_t)2048 * 3072;
    bf16* VvalT   = ws; ws += (size_t)256 * 128 * 512;
    bf16* QvalT   = ws; ws += (size_t)256 * 128 * 512;
    // 432 MiB of d_ws

    // 1) convert inputs to bf16 into concat-left (also the GEMM A operands)
    cvt_cols_k<<<8192, 256, 0, stream>>>(v, vcat, 8, 4096, 8192 * 256);
    cvt_cols_k<<<4096, 256, 0, stream>>>(q, qcat, 7, 3072, 8192 * 128);

    // 2) weight convert+transpose (f32 R x C -> bf16 C x R)
    cvt_transpose_k<<<dim3(96, 32), 256, 0, stream>>>(Wv,  (unsigned short*)WvT,  6144, 2048);
    cvt_transpose_k<<<dim3(96, 16), 256, 0, stream>>>(Wq,  (unsigned short*)WqT,  6144, 1024);
    cvt_transpose_k<<<dim3(32, 64), 256, 0, stream>>>(Wvo, (unsigned short*)WvoT, 2048, 4096);
    cvt_transpose_k<<<dim3(32, 48), 256, 0, stream>>>(Wqo, (unsigned short*)WqoT, 2048, 3072);

    // 3) input projections (256x256 tiles)
    gemm_bt<bf16><<<dim3(24, 32), 512, 0, stream>>>(vcat, WvT, bv, vm, v_trans, 2048, 4096, 2048, 6144);
    gemm_bt<bf16><<<dim3(24, 32), 512, 0, stream>>>(qcat, WqT, bq, qm, q_trans, 1024, 3072, 1024, 6144);

    // 4) value-slice transposes: [b,n,h,d] -> [bh][d][n]
    transpose_k<<<dim3(2, 8, 256), 256, 0, stream>>>((const unsigned short*)(v_trans + 4096), (unsigned short*)VvalT,
                                                     6144, 512, (size_t)512 * 6144, 128, 65536);
    transpose_k<<<dim3(2, 8, 256), 256, 0, stream>>>((const unsigned short*)(q_trans + 4096), (unsigned short*)QvalT,
                                                     6144, 512, (size_t)512 * 6144, 128, 65536);

    // 5) cross attention
    attn_k<<<dim3(16, 256), 128, 0, stream>>>(v_trans + 2048, q_trans, QvalT, qm, vcat,
                                              512, 512, 6144, 6144, 4096, 2048);
    attn_k<<<dim3(16, 256), 128, 0, stream>>>(q_trans + 2048, v_trans, VvalT, vm, qcat,
                                              512, 512, 6144, 6144, 3072, 1024);

    // 6) output projections -> d_out (f32, LDS-staged stores)
    gemm_bt<float><<<dim3(8, 32), 512, 0, stream>>>(vcat, WvoT, bvo, nullptr, out_v, 4096, 4096, 4096, 2048);
    gemm_bt<float><<<dim3(8, 32), 512, 0, stream>>>(qcat, WqoT, bqo, nullptr, out_q, 3072, 3072, 3072, 2048);
}